// Round 4
// baseline (174.607 us; speedup 1.0000x reference)
//
#include <hip/hip_runtime.h>

typedef __bf16 bf16x8 __attribute__((ext_vector_type(8)));
typedef float f32x4 __attribute__((ext_vector_type(4)));
typedef unsigned short u16x8 __attribute__((ext_vector_type(8)));
typedef unsigned short u16x4 __attribute__((ext_vector_type(4)));

static __device__ __forceinline__ unsigned short f2bf(float f){
  __bf16 h = (__bf16)f;
  return __builtin_bit_cast(unsigned short, h);
}
static __device__ __forceinline__ f32x4 mfma16(bf16x8 a, bf16x8 b, f32x4 c){
  return __builtin_amdgcn_mfma_f32_16x16x32_bf16(a, b, c, 0, 0, 0);
}

#define WAVES 4
#define PTSW  4

// ---------------- prep: 44 weight fragments into ws ----------------
// frags m: 0-7 kW1, 8-15 vW1, 16-23 kW2, 24-31 vW2, 32-39 pW2, 40-43 pW1-frag(tile t)
// entry (m*64+lane) is one u16x8 (per-lane 16B fragment).
__global__ void pt_prep(const float* __restrict__ kW1, const float* __restrict__ vW1,
                        const float* __restrict__ kW2, const float* __restrict__ vW2,
                        const float* __restrict__ pW2, const float* __restrict__ pW1,
                        const float* __restrict__ pb1, unsigned short* __restrict__ ws){
  const int b = blockIdx.x, lane = threadIdx.x;
  const int ln = lane & 15, g = lane >> 4;
  u16x8 v = {0,0,0,0,0,0,0,0};
  if (b < 40){
    const float* W = (b < 8) ? kW1 : (b < 16) ? vW1 : (b < 24) ? kW2 : (b < 32) ? vW2 : pW2;
    const int f = b & 7, t = f >> 1, cc = f & 1;
    const int col = ln + 16 * t;
    const int k0  = 8 * g + 32 * cc;
#pragma unroll
    for (int j = 0; j < 8; ++j) v[j] = f2bf(W[(k0 + j) * 64 + col]);
  } else {
    // pW1 fragment for tile t: A[row=ch=16t+ln][k] = {pW1[0..2][ch], pb1[ch]} on g==0
    const int t = b - 40;
    if (g == 0){
      const int ch = 16 * t + ln;
      v[0] = f2bf(pW1[ch]); v[1] = f2bf(pW1[64 + ch]);
      v[2] = f2bf(pW1[128 + ch]); v[3] = f2bf(pb1[ch]);
    }
  }
  *(u16x8*)(ws + (size_t)(b * 64 + lane) * 8) = v;
}

// ---------------- main fused kernel: 4 waves x 4 points per block ----------------
__global__ __launch_bounds__(256, 2) void pt_fused(
    const float* __restrict__ xn, const float* __restrict__ p, const float* __restrict__ pn,
    const float* __restrict__ kb1, const float* __restrict__ vb1,
    const float* __restrict__ kb2, const float* __restrict__ vb2, const float* __restrict__ pb2,
    const unsigned short* __restrict__ ws, float* __restrict__ out)
{
  const int tid = threadIdx.x;
  const int wid = tid >> 6, lane = tid & 63, ln = lane & 15, g = lane >> 4;

  __shared__ unsigned short sW[16 * 64 * 8];              // wv2 (f 0-7) + wp2 (f 8-15), 16KB
  __shared__ unsigned short sStage[WAVES][2][3 * 1024];   // per-wave double-buffered K,V,P staging

  // cooperative prologue: copy wv2+wp2 frags (m=24..39) into LDS
  for (int i = tid; i < 1024; i += 256)
    ((u16x8*)sW)[i] = *(const u16x8*)(ws + (size_t)(24 * 64 + i) * 8);
  __syncthreads();

  // per-wave register weights (coalesced b128 loads from ws)
  bf16x8 wk1[4][2], wv1[4][2], wk2[4][2];
  u16x4 wp1q[4];
#pragma unroll
  for (int t = 0; t < 4; ++t){
#pragma unroll
    for (int cc = 0; cc < 2; ++cc){
      const int f = 2 * t + cc;
      wk1[t][cc] = __builtin_bit_cast(bf16x8, *(const u16x8*)(ws + (size_t)(( 0 + f) * 64 + lane) * 8));
      wv1[t][cc] = __builtin_bit_cast(bf16x8, *(const u16x8*)(ws + (size_t)(( 8 + f) * 64 + lane) * 8));
      wk2[t][cc] = __builtin_bit_cast(bf16x8, *(const u16x8*)(ws + (size_t)((16 + f) * 64 + lane) * 8));
    }
    wp1q[t] = *(const u16x4*)(ws + (size_t)((40 + t) * 64 + lane) * 8);
  }

  // layer-1 biases in C/D layout (f32x4 at ch = 16t+4g), layer-2 biases per lane col
  f32x4 bk1[4], bv1[4];
  float bk2[4], bv2[4], bp2[4];
#pragma unroll
  for (int t = 0; t < 4; ++t){
    bk1[t] = *(const f32x4*)(kb1 + 16 * t + 4 * g);
    bv1[t] = *(const f32x4*)(vb1 + 16 * t + 4 * g);
    const int c = ln + 16 * t;
    bk2[t] = kb2[c]; bv2[t] = vb2[c]; bp2[t] = pb2[c];
  }

  const size_t p0 = ((size_t)blockIdx.x * WAVES + wid) * PTSW;
  unsigned short* myStage = &sStage[wid][0][0];
  const size_t xbase = p0 * 1024 + (size_t)ln * 64 + g * 8;
  const int swz = (ln & 7) << 3;

  float4 nx0, nx1, nx2, nx3; float np0, np1, np2;
#define PREF(j) { const float* xp = xn + xbase + (size_t)(j) * 1024;                          \
    nx0 = *(const float4*)(xp);      nx1 = *(const float4*)(xp + 4);                          \
    nx2 = *(const float4*)(xp + 32); nx3 = *(const float4*)(xp + 36);                         \
    const float* q = pn + (p0 + (j)) * 48 + ln * 3; np0 = q[0]; np1 = q[1]; np2 = q[2]; }

  PREF(0);

#pragma unroll 2
  for (int i = 0; i < PTSW; ++i){
    const size_t pt = p0 + i;

    // convert prefetched point (vmcnt consumer)
    u16x8 a0u, a1u;
    a0u[0]=f2bf(nx0.x); a0u[1]=f2bf(nx0.y); a0u[2]=f2bf(nx0.z); a0u[3]=f2bf(nx0.w);
    a0u[4]=f2bf(nx1.x); a0u[5]=f2bf(nx1.y); a0u[6]=f2bf(nx1.z); a0u[7]=f2bf(nx1.w);
    a1u[0]=f2bf(nx2.x); a1u[1]=f2bf(nx2.y); a1u[2]=f2bf(nx2.z); a1u[3]=f2bf(nx2.w);
    a1u[4]=f2bf(nx3.x); a1u[5]=f2bf(nx3.y); a1u[6]=f2bf(nx3.z); a1u[7]=f2bf(nx3.w);
    const float px = p[pt * 3 + 0], py = p[pt * 3 + 1], pz = p[pt * 3 + 2];
    u16x8 apu = {0,0,0,0,0,0,0,0};
    if (g == 0){
      apu[0] = f2bf(px - np0); apu[1] = f2bf(py - np1);
      apu[2] = f2bf(pz - np2); apu[3] = 0x3F80u;   // bias rides k=3
    }
    const bf16x8 a0 = __builtin_bit_cast(bf16x8, a0u);
    const bf16x8 a1 = __builtin_bit_cast(bf16x8, a1u);
    const bf16x8 ap = __builtin_bit_cast(bf16x8, apu);

    if (i + 1 < PTSW) PREF(i + 1);   // next point's loads in flight during compute

    unsigned short* bufK = myStage + (i & 1) * 3072;
    unsigned short* bufV = bufK + 1024;
    unsigned short* bufP = bufK + 2048;

    // ---- layer 1 (swapped operands -> [ch][n] layout), ReLU+cvt, stage ----
#pragma unroll
    for (int t = 0; t < 4; ++t){
      f32x4 hk = bk1[t];
      hk = mfma16(wk1[t][0], a0, hk); hk = mfma16(wk1[t][1], a1, hk);
      f32x4 hv = bv1[t];
      hv = mfma16(wv1[t][0], a0, hv); hv = mfma16(wv1[t][1], a1, hv);
      u16x8 w1u = {wp1q[t][0], wp1q[t][1], wp1q[t][2], wp1q[t][3], 0, 0, 0, 0};
      f32x4 z = {0.f, 0.f, 0.f, 0.f};
      f32x4 hp = mfma16(__builtin_bit_cast(bf16x8, w1u), ap, z);

      const int wa = ln * 64 + ((16 * t + 4 * g) ^ swz);
      u16x4 qk, qv, qp;
#pragma unroll
      for (int ii = 0; ii < 4; ++ii){
        qk[ii] = f2bf(fmaxf(hk[ii], 0.f));
        qv[ii] = f2bf(fmaxf(hv[ii], 0.f));
        qp[ii] = f2bf(fmaxf(hp[ii], 0.f));
      }
      *(u16x4*)(bufK + wa) = qk; *(u16x4*)(bufV + wa) = qv; *(u16x4*)(bufP + wa) = qp;
    }

    // ---- layer-2 A fragments from staging ----
    const int rb = ln * 64;
    const int o0 = (8 * g) ^ swz, o1 = (8 * g + 32) ^ swz;
    const bf16x8 fk0 = __builtin_bit_cast(bf16x8, *(const u16x8*)(bufK + rb + o0));
    const bf16x8 fk1 = __builtin_bit_cast(bf16x8, *(const u16x8*)(bufK + rb + o1));
    const bf16x8 fv0 = __builtin_bit_cast(bf16x8, *(const u16x8*)(bufV + rb + o0));
    const bf16x8 fv1 = __builtin_bit_cast(bf16x8, *(const u16x8*)(bufV + rb + o1));
    const bf16x8 fp0 = __builtin_bit_cast(bf16x8, *(const u16x8*)(bufP + rb + o0));
    const bf16x8 fp1 = __builtin_bit_cast(bf16x8, *(const u16x8*)(bufP + rb + o1));

    // ---- layer 2 + softmax (no max-sub: |logit| small) ----
    float oval = 0.f;
#pragma unroll
    for (int t = 0; t < 4; ++t){
      f32x4 kf = {bk2[t], bk2[t], bk2[t], bk2[t]};
      kf = mfma16(fk0, wk2[t][0], kf); kf = mfma16(fk1, wk2[t][1], kf);
      const bf16x8 wv2a = __builtin_bit_cast(bf16x8, *(const u16x8*)(sW + ((2 * t) * 64 + lane) * 8));
      const bf16x8 wv2b = __builtin_bit_cast(bf16x8, *(const u16x8*)(sW + ((2 * t + 1) * 64 + lane) * 8));
      f32x4 vf = {bv2[t], bv2[t], bv2[t], bv2[t]};
      vf = mfma16(fv0, wv2a, vf); vf = mfma16(fv1, wv2b, vf);
      // wp2 frag f=8+2t(+1) lives at sW entry (f*64+lane) -- no extra offset
      const bf16x8 wp2a = __builtin_bit_cast(bf16x8, *(const u16x8*)(sW + ((8 + 2 * t) * 64 + lane) * 8));
      const bf16x8 wp2b = __builtin_bit_cast(bf16x8, *(const u16x8*)(sW + ((8 + 2 * t + 1) * 64 + lane) * 8));
      f32x4 pe = {bp2[t], bp2[t], bp2[t], bp2[t]};
      pe = mfma16(fp0, wp2a, pe); pe = mfma16(fp1, wp2b, pe);

      const float c = 1.4426950408889634f;
      const float w0 = exp2f((pe[0] - kf[0]) * c), w1 = exp2f((pe[1] - kf[1]) * c);
      const float w2 = exp2f((pe[2] - kf[2]) * c), w3 = exp2f((pe[3] - kf[3]) * c);
      float s = w0 + w1 + w2 + w3;
      float num = w0 * (vf[0] + pe[0]) + w1 * (vf[1] + pe[1])
                + w2 * (vf[2] + pe[2]) + w3 * (vf[3] + pe[3]);
      s   += __shfl_xor(s, 16);   s   += __shfl_xor(s, 32);
      num += __shfl_xor(num, 16); num += __shfl_xor(num, 32);
      const float res = num * __builtin_amdgcn_rcpf(s);
      oval = (g == t) ? res : oval;
    }
    out[pt * 64 + lane] = oval;
  }
#undef PREF
}

static_assert((15 * 64 + 63) * 8 + 8 <= 16 * 64 * 8, "sW bounds");

extern "C" void kernel_launch(void* const* d_in, const int* in_sizes, int n_in,
                              void* d_out, int out_size, void* d_ws, size_t ws_size,
                              hipStream_t stream){
  (void)n_in; (void)ws_size; (void)out_size;
  const float* xn  = (const float*)d_in[1];
  const float* p   = (const float*)d_in[2];
  const float* pn  = (const float*)d_in[3];
  const float* kW1 = (const float*)d_in[8];
  const float* kb1 = (const float*)d_in[9];
  const float* kW2 = (const float*)d_in[10];
  const float* kb2 = (const float*)d_in[11];
  const float* vW1 = (const float*)d_in[12];
  const float* vb1 = (const float*)d_in[13];
  const float* vW2 = (const float*)d_in[14];
  const float* vb2 = (const float*)d_in[15];
  const float* pW1 = (const float*)d_in[16];
  const float* pb1 = (const float*)d_in[17];
  const float* pW2 = (const float*)d_in[18];
  const float* pb2 = (const float*)d_in[19];
  unsigned short* ws = (unsigned short*)d_ws;
  float* o = (float*)d_out;

  hipLaunchKernelGGL(pt_prep, dim3(44), dim3(64), 0, stream,
                     kW1, vW1, kW2, vW2, pW2, pW1, pb1, ws);

  const int BN = in_sizes[1] / (16 * 64);       // B*N = 32768
  dim3 grid(BN / (WAVES * PTSW));               // 2048 blocks x 256 threads
  hipLaunchKernelGGL(pt_fused, grid, dim3(256), 0, stream,
                     xn, p, pn, kb1, vb1, kb2, vb2, pb2, ws, o);
}

// Round 5
// 73.964 us; speedup vs baseline: 2.3607x; 2.3607x over previous
//
#include <hip/hip_runtime.h>

typedef __bf16 bf16x8 __attribute__((ext_vector_type(8)));
typedef float f32x4 __attribute__((ext_vector_type(4)));
typedef unsigned short u16x8 __attribute__((ext_vector_type(8)));
typedef unsigned short u16x4 __attribute__((ext_vector_type(4)));

static __device__ __forceinline__ unsigned short f2bf(float f){
  __bf16 h = (__bf16)f;
  return __builtin_bit_cast(unsigned short, h);
}
static __device__ __forceinline__ f32x4 mfma16(bf16x8 a, bf16x8 b, f32x4 c){
  return __builtin_amdgcn_mfma_f32_16x16x32_bf16(a, b, c, 0, 0, 0);
}

#define PTS 16   // points per wave

// ws layout (u16 units):
//   [0,16384)      : 32 reg frags: kW1 0-7, vW1 8-15, kW2 16-23, vW2 24-31 (entry (f*64+lane)*8)
//   [16384,20480)  : pW2 frags 0-7
//   [20480,20992)  : pos-table: 256 f32 = per lane {pW1[0..2][ch], pb1[ch]} for ch=32c+8g+j
//   [20992,21248)  : kb1[64], vb1[64] f32
__global__ void pt_prep(const float* __restrict__ kW1, const float* __restrict__ vW1,
                        const float* __restrict__ kW2, const float* __restrict__ vW2,
                        const float* __restrict__ pW2, const float* __restrict__ pW1,
                        const float* __restrict__ pb1, const float* __restrict__ kb1,
                        const float* __restrict__ vb1, unsigned short* __restrict__ ws){
  const int b = blockIdx.x, lane = threadIdx.x;
  const int ln = lane & 15, g = lane >> 4;
  if (b < 40){
    const float* W = (b < 8) ? kW1 : (b < 16) ? vW1 : (b < 24) ? kW2 : (b < 32) ? vW2 : pW2;
    const int f = b & 7, t = f >> 1, cc = f & 1;
    const int col = ln + 16 * t;
    const int k0  = 8 * g + 32 * cc;
    u16x8 v;
#pragma unroll
    for (int j = 0; j < 8; ++j) v[j] = f2bf(W[(k0 + j) * 64 + col]);
    unsigned short* dst = (b < 32) ? (ws + (size_t)(b * 64 + lane) * 8)
                                   : (ws + 16384 + (size_t)((b - 32) * 64 + lane) * 8);
    *(u16x8*)dst = v;
  } else if (b == 40){
    // pos-table: lane = g*16 + c*8 + j ; entry = {pW1[0][ch],pW1[1][ch],pW1[2][ch],pb1[ch]}
    const int c = (lane >> 3) & 1, j = lane & 7;
    const int ch = 32 * c + 8 * g + j;
    float* wsF = (float*)(ws + 20480);
    f32x4 v; v[0] = pW1[ch]; v[1] = pW1[64 + ch]; v[2] = pW1[128 + ch]; v[3] = pb1[ch];
    *(f32x4*)(wsF + lane * 4) = v;
  } else {
    float* wsB = (float*)(ws + 20992);
    wsB[lane] = kb1[lane]; wsB[64 + lane] = vb1[lane];
  }
}

// ---------------- main fused kernel ----------------
// 512 blocks x 256 thr (4 waves); 2 blocks/CU pinned via waves_per_eu(2,2) -> 256 VGPR budget.
__global__ __launch_bounds__(256) __attribute__((amdgpu_waves_per_eu(2, 2)))
void pt_fused(const float* __restrict__ xn, const float* __restrict__ p,
              const float* __restrict__ pn,
              const float* __restrict__ kb2, const float* __restrict__ vb2,
              const float* __restrict__ pb2,
              const unsigned short* __restrict__ ws, float* __restrict__ out)
{
  const int tid = threadIdx.x;
  const int wid = tid >> 6, lane = tid & 63, ln = lane & 15, g = lane >> 4;

  // manual LDS partition (u16 units):
  //   [0,4096)      sWp2 frags   (8 KB, persistent)
  //   [4096,4608)   sPos (256 f32)
  //   [4608,4864)   sB1  (128 f32: kb1, vb1)
  //   [4864,13056)  sStage: 4 waves x (K 1024 + V 1024)
  //   [13056,29440) sFr: 32 reg-weight frags (prologue only)
  __shared__ unsigned short sm[29440] __attribute__((aligned(16)));
  unsigned short* sWp2 = sm;
  const float* sPosF   = (const float*)(sm + 4096);
  const float* sB1f    = (const float*)(sm + 4608);
  unsigned short* sStage = sm + 4864;
  unsigned short* sFr    = sm + 13056;

  // ---- cooperative prologue: ws -> LDS (fully coalesced b128) ----
  for (int i = tid; i < 608; i += 256)          // sWp2 + sPos + sB1 (contiguous in ws)
    *(u16x8*)(sm + i * 8) = *(const u16x8*)(ws + 16384 + (size_t)i * 8);
  for (int i = tid; i < 2048; i += 256)         // 32 reg frags
    *(u16x8*)(sFr + i * 8) = *(const u16x8*)(ws + (size_t)i * 8);
  __syncthreads();

  // per-wave register weights from LDS
  bf16x8 wk1[4][2], wv1[4][2], wk2[4][2], wv2[4][2];
#pragma unroll
  for (int t = 0; t < 4; ++t)
#pragma unroll
    for (int cc = 0; cc < 2; ++cc){
      const int f = 2 * t + cc;
      wk1[t][cc] = __builtin_bit_cast(bf16x8, *(const u16x8*)(sFr + (( 0 + f) * 64 + lane) * 8));
      wv1[t][cc] = __builtin_bit_cast(bf16x8, *(const u16x8*)(sFr + (( 8 + f) * 64 + lane) * 8));
      wk2[t][cc] = __builtin_bit_cast(bf16x8, *(const u16x8*)(sFr + ((16 + f) * 64 + lane) * 8));
      wv2[t][cc] = __builtin_bit_cast(bf16x8, *(const u16x8*)(sFr + ((24 + f) * 64 + lane) * 8));
    }

  float bk2[4], bv2[4], bp2[4];
#pragma unroll
  for (int t = 0; t < 4; ++t){
    const int c = ln + 16 * t;
    bk2[t] = kb2[c]; bv2[t] = vb2[c]; bp2[t] = pb2[c];
  }

  const size_t p0 = ((size_t)blockIdx.x * 4 + wid) * PTS;
  unsigned short* bufK = sStage + wid * 2048;
  unsigned short* bufV = bufK + 1024;
  const size_t xbase = p0 * 1024 + (size_t)ln * 64 + g * 8;
  const int swz = (ln & 7) << 3;

  float4 nx0, nx1, nx2, nx3; float np0, np1, np2, pp0, pp1, pp2;
#define PREF(j) { const float* xp = xn + xbase + (size_t)(j) * 1024;                          \
    nx0 = *(const float4*)(xp);      nx1 = *(const float4*)(xp + 4);                          \
    nx2 = *(const float4*)(xp + 32); nx3 = *(const float4*)(xp + 36);                         \
    const float* q = pn + (p0 + (j)) * 48 + ln * 3; np0 = q[0]; np1 = q[1]; np2 = q[2];       \
    const float* pq = p + (p0 + (j)) * 3; pp0 = pq[0]; pp1 = pq[1]; pp2 = pq[2]; }

  PREF(0);

#pragma unroll 1
  for (int i = 0; i < PTS; ++i){
    const size_t pt = p0 + i;

    // consume prefetched point
    u16x8 a0u, a1u;
    a0u[0]=f2bf(nx0.x); a0u[1]=f2bf(nx0.y); a0u[2]=f2bf(nx0.z); a0u[3]=f2bf(nx0.w);
    a0u[4]=f2bf(nx1.x); a0u[5]=f2bf(nx1.y); a0u[6]=f2bf(nx1.z); a0u[7]=f2bf(nx1.w);
    a1u[0]=f2bf(nx2.x); a1u[1]=f2bf(nx2.y); a1u[2]=f2bf(nx2.z); a1u[3]=f2bf(nx2.w);
    a1u[4]=f2bf(nx3.x); a1u[5]=f2bf(nx3.y); a1u[6]=f2bf(nx3.z); a1u[7]=f2bf(nx3.w);
    const float dx = pp0 - np0, dy = pp1 - np1, dz = pp2 - np2;
    const bf16x8 a0 = __builtin_bit_cast(bf16x8, a0u);
    const bf16x8 a1 = __builtin_bit_cast(bf16x8, a1u);

    if (i + 1 < PTS) PREF(i + 1);   // next point's loads in flight

    // ---- L1 K,V (swapped operands -> h[ch][n]), ReLU+cvt, stage swizzled ----
#pragma unroll
    for (int t = 0; t < 4; ++t){
      f32x4 hk = *(const f32x4*)(sB1f + 16 * t + 4 * g);
      hk = mfma16(wk1[t][0], a0, hk); hk = mfma16(wk1[t][1], a1, hk);
      f32x4 hv = *(const f32x4*)(sB1f + 64 + 16 * t + 4 * g);
      hv = mfma16(wv1[t][0], a0, hv); hv = mfma16(wv1[t][1], a1, hv);
      const int wa = ln * 64 + ((16 * t + 4 * g) ^ swz);
      u16x4 qk, qv;
#pragma unroll
      for (int ii = 0; ii < 4; ++ii){
        qk[ii] = f2bf(fmaxf(hk[ii], 0.f));
        qv[ii] = f2bf(fmaxf(hv[ii], 0.f));
      }
      *(u16x4*)(bufK + wa) = qk; *(u16x4*)(bufV + wa) = qv;
    }

    // ---- PE layer-1 on VALU: directly builds L2 A-frag (k=8g+j, n=ln) ----
    u16x8 fp0u, fp1u;
#pragma unroll
    for (int c = 0; c < 2; ++c)
#pragma unroll
      for (int j = 0; j < 8; ++j){
        const f32x4 w = *(const f32x4*)(sPosF + ((g * 2 + c) * 8 + j) * 4);
        float h = fmaf(w[0], dx, fmaf(w[1], dy, fmaf(w[2], dz, w[3])));
        const unsigned short hb = f2bf(fmaxf(h, 0.f));
        if (c == 0) fp0u[j] = hb; else fp1u[j] = hb;
      }
    const bf16x8 fp0 = __builtin_bit_cast(bf16x8, fp0u);
    const bf16x8 fp1 = __builtin_bit_cast(bf16x8, fp1u);

    // ---- staged K,V -> L2 A-frags ----
    const int rb = ln * 64;
    const int o0 = (8 * g) ^ swz, o1 = (8 * g + 32) ^ swz;
    const bf16x8 fk0 = __builtin_bit_cast(bf16x8, *(const u16x8*)(bufK + rb + o0));
    const bf16x8 fk1 = __builtin_bit_cast(bf16x8, *(const u16x8*)(bufK + rb + o1));
    const bf16x8 fv0 = __builtin_bit_cast(bf16x8, *(const u16x8*)(bufV + rb + o0));
    const bf16x8 fv1 = __builtin_bit_cast(bf16x8, *(const u16x8*)(bufV + rb + o1));

    // ---- layer 2 + softmax over neighbors ----
    float oval = 0.f;
#pragma unroll
    for (int t = 0; t < 4; ++t){
      f32x4 kf = {bk2[t], bk2[t], bk2[t], bk2[t]};
      kf = mfma16(fk0, wk2[t][0], kf); kf = mfma16(fk1, wk2[t][1], kf);
      f32x4 vf = {bv2[t], bv2[t], bv2[t], bv2[t]};
      vf = mfma16(fv0, wv2[t][0], vf); vf = mfma16(fv1, wv2[t][1], vf);
      const bf16x8 wp2a = __builtin_bit_cast(bf16x8, *(const u16x8*)(sWp2 + ((2 * t) * 64 + lane) * 8));
      const bf16x8 wp2b = __builtin_bit_cast(bf16x8, *(const u16x8*)(sWp2 + ((2 * t + 1) * 64 + lane) * 8));
      f32x4 pe = {bp2[t], bp2[t], bp2[t], bp2[t]};
      pe = mfma16(fp0, wp2a, pe); pe = mfma16(fp1, wp2b, pe);

      const float c = 1.4426950408889634f;
      const float w0 = exp2f((pe[0] - kf[0]) * c), w1 = exp2f((pe[1] - kf[1]) * c);
      const float w2 = exp2f((pe[2] - kf[2]) * c), w3 = exp2f((pe[3] - kf[3]) * c);
      float s = w0 + w1 + w2 + w3;
      float num = w0 * (vf[0] + pe[0]) + w1 * (vf[1] + pe[1])
                + w2 * (vf[2] + pe[2]) + w3 * (vf[3] + pe[3]);
      s   += __shfl_xor(s, 16);   s   += __shfl_xor(s, 32);
      num += __shfl_xor(num, 16); num += __shfl_xor(num, 32);
      const float res = num * __builtin_amdgcn_rcpf(s);
      oval = (g == t) ? res : oval;
    }
    out[pt * 64 + lane] = oval;
  }
#undef PREF
}

extern "C" void kernel_launch(void* const* d_in, const int* in_sizes, int n_in,
                              void* d_out, int out_size, void* d_ws, size_t ws_size,
                              hipStream_t stream){
  (void)n_in; (void)ws_size; (void)out_size;
  const float* xn  = (const float*)d_in[1];
  const float* p   = (const float*)d_in[2];
  const float* pn  = (const float*)d_in[3];
  const float* kW1 = (const float*)d_in[8];
  const float* kb1 = (const float*)d_in[9];
  const float* kW2 = (const float*)d_in[10];
  const float* kb2 = (const float*)d_in[11];
  const float* vW1 = (const float*)d_in[12];
  const float* vb1 = (const float*)d_in[13];
  const float* vW2 = (const float*)d_in[14];
  const float* vb2 = (const float*)d_in[15];
  const float* pW1 = (const float*)d_in[16];
  const float* pb1 = (const float*)d_in[17];
  const float* pW2 = (const float*)d_in[18];
  const float* pb2 = (const float*)d_in[19];
  unsigned short* ws = (unsigned short*)d_ws;
  float* o = (float*)d_out;

  hipLaunchKernelGGL(pt_prep, dim3(42), dim3(64), 0, stream,
                     kW1, vW1, kW2, vW2, pW2, pW1, pb1, kb1, vb1, ws);

  const int BN = in_sizes[1] / (16 * 64);         // B*N = 32768
  dim3 grid(BN / (4 * PTS));                      // 512 blocks x 256 threads
  hipLaunchKernelGGL(pt_fused, grid, dim3(256), 0, stream,
                     xn, p, pn, kb2, vb2, pb2, ws, o);
}